// Round 10
// baseline (156.956 us; speedup 1.0000x reference)
//
#include <hip/hip_runtime.h>
#include <hip/hip_fp16.h>

#define BSZ   1024
#define INDIM 768
#define PROJ  9216     // 256*6*6
#define NCAP  512
#define NCLS  5
#define K2    2304     // conv GEMM K = 9 taps * 256 ic

typedef __bf16    bf16x8 __attribute__((ext_vector_type(8)));
typedef _Float16  f16x8  __attribute__((ext_vector_type(8)));
typedef float     f32x4  __attribute__((ext_vector_type(4)));
typedef _Float16  h2     __attribute__((ext_vector_type(2)));

static __device__ __forceinline__ unsigned short f2bf(float f) {
  unsigned int x = __float_as_uint(f);
  return (unsigned short)((x + 0x7fffu + ((x >> 16) & 1u)) >> 16);
}
static __device__ __forceinline__ float bf2f(unsigned int u) {
  return __uint_as_float(u << 16);
}
static __device__ __forceinline__ unsigned short f2h(float f) {
  return __builtin_bit_cast(unsigned short, (_Float16)f);
}

// global -> LDS direct (16B per lane)
static __device__ __forceinline__ void gload16(const void* g, void* l) {
  auto gp = reinterpret_cast<const unsigned int __attribute__((address_space(1)))*>(
      (unsigned long long)g);
  auto lp = reinterpret_cast<unsigned int __attribute__((address_space(3)))*>(
      (unsigned long long)l);
  __builtin_amdgcn_global_load_lds(gp, lp, 16, 0, 0);
}

// =====================================================================
// Unified bf16 MFMA GEMM (unchanged — passing)
// =====================================================================
template <int RELU, int OBF16>
__global__ __launch_bounds__(256) void mfma_gemm(
    const unsigned short* __restrict__ A,   // [M][K] bf16
    const unsigned short* __restrict__ Bt,  // [N][K] bf16
    const float* __restrict__ bias,         // [N]
    void* __restrict__ Cout,                // [M][N] f32 or bf16
    int M, int N, int K) {
  __shared__ __align__(16) unsigned short smem[16384];
  const int t    = threadIdx.x;
  const int bn   = blockIdx.x * 128;
  const int bm   = blockIdx.y * 128;
  const int lane = t & 63;
  const int wid  = t >> 6;
  const int wm   = (wid >> 1) * 64;
  const int wn   = (wid & 1) * 64;
  const int l15  = lane & 15;
  const int kb   = lane >> 4;

  const int r0 = t >> 2,         kc = t & 3;
  const int r1 = (t + 256) >> 2;
  const int gk0 = ((kc ^ (r0 & 3)) << 3);
  const int gk1 = ((kc ^ (r1 & 3)) << 3);

  const unsigned short* Ar0 = A  + (size_t)(bm + r0) * K + gk0;
  const unsigned short* Ar1 = A  + (size_t)(bm + r1) * K + gk1;
  const unsigned short* Br0 = Bt + (size_t)(bn + r0) * K + gk0;
  const unsigned short* Br1 = Bt + (size_t)(bn + r1) * K + gk1;

  int aoff[4], boff[4];
#pragma unroll
  for (int i = 0; i < 4; ++i) {
    const int ra = wm + i * 16 + l15;
    aoff[i] = ra * 32 + ((kb ^ (ra & 3)) << 3);
    const int rb = wn + i * 16 + l15;
    boff[i] = 4096 + rb * 32 + ((kb ^ (rb & 3)) << 3);
  }

  f32x4 acc[4][4];
#pragma unroll
  for (int i = 0; i < 4; ++i)
#pragma unroll
    for (int j = 0; j < 4; ++j)
#pragma unroll
      for (int q = 0; q < 4; ++q) acc[i][j][q] = 0.f;

  const int nk = K >> 5;
  gload16(Ar0, &smem[t * 8]);
  gload16(Ar1, &smem[(t + 256) * 8]);
  gload16(Br0, &smem[4096 + t * 8]);
  gload16(Br1, &smem[4096 + (t + 256) * 8]);
  __syncthreads();

  int buf = 0;
  for (int ks = 0; ks < nk; ++ks) {
    if (ks + 1 < nk) {
      const int k = (ks + 1) << 5;
      const int o = (buf ^ 1) * 8192;
      gload16(Ar0 + k, &smem[o + t * 8]);
      gload16(Ar1 + k, &smem[o + (t + 256) * 8]);
      gload16(Br0 + k, &smem[o + 4096 + t * 8]);
      gload16(Br1 + k, &smem[o + 4096 + (t + 256) * 8]);
    }
    const unsigned short* base = &smem[buf * 8192];
    bf16x8 af[4], bfr[4];
#pragma unroll
    for (int i = 0; i < 4; ++i) {
      af[i]  = *(const bf16x8*)(base + aoff[i]);
      bfr[i] = *(const bf16x8*)(base + boff[i]);
    }
#pragma unroll
    for (int i = 0; i < 4; ++i)
#pragma unroll
      for (int j = 0; j < 4; ++j)
        acc[i][j] = __builtin_amdgcn_mfma_f32_16x16x32_bf16(af[i], bfr[j], acc[i][j], 0, 0, 0);
    __syncthreads();
    buf ^= 1;
  }

#pragma unroll
  for (int j = 0; j < 4; ++j) {
    const int col = bn + wn + j * 16 + l15;
    const float bv = bias[col];
#pragma unroll
    for (int i = 0; i < 4; ++i) {
#pragma unroll
      for (int q = 0; q < 4; ++q) {
        const int row = bm + wm + i * 16 + kb * 4 + q;
        float v = acc[i][j][q] + bv;
        if (RELU) v = fmaxf(v, 0.f);
        if (OBF16) ((unsigned short*)Cout)[(size_t)row * N + col] = f2bf(v);
        else       ((float*)Cout)[(size_t)row * N + col] = v;
      }
    }
  }
}

// =====================================================================
// conv_gemm_sq (unchanged — passing)
// =====================================================================
__global__ __launch_bounds__(256) void conv_gemm_sq(
    const unsigned short* __restrict__ ht,   // [1024][36][256] bf16
    const unsigned short* __restrict__ Wt2,  // [256][2304] bf16
    const float* __restrict__ convB,         // [256]
    unsigned short* __restrict__ U) {        // [1024][32][16][8] fp16
  __shared__ __align__(16) unsigned short smem[24576];
  const int t    = threadIdx.x;
  const int bn   = blockIdx.x * 128;
  const int bm   = blockIdx.y * 64;
  const int lane = t & 63, wid = t >> 6;
  const int l15  = lane & 15, kb = lane >> 4;

  const unsigned short* asrc[2];
#pragma unroll
  for (int cc = 0; cc < 2; ++cc) {
    const int c = t + cc * 256;
    const int row = c >> 3, seg = c & 7;
    const int gr = bm + row, b = gr >> 4, p = gr & 15;
    const int spb = (p >> 2) * 6 + (p & 3);
    asrc[cc] = ht + (size_t)b * PROJ + spb * 256 + ((seg ^ (row & 7)) << 3);
  }
  const unsigned short* bsrc[4];
#pragma unroll
  for (int cc = 0; cc < 4; ++cc) {
    const int c = t + cc * 256;
    const int row = c >> 3, seg = c & 7;
    bsrc[cc] = Wt2 + (size_t)(bn + row) * K2 + ((seg ^ (row & 7)) << 3);
  }

  int aoff[4][2], boff[2][2];
#pragma unroll
  for (int i = 0; i < 4; ++i)
#pragma unroll
    for (int kk = 0; kk < 2; ++kk) {
      const int row = i * 16 + l15, seg = kk * 4 + kb;
      aoff[i][kk] = row * 64 + ((seg ^ (row & 7)) << 3);
    }
#pragma unroll
  for (int j = 0; j < 2; ++j)
#pragma unroll
    for (int kk = 0; kk < 2; ++kk) {
      const int row = wid * 32 + j * 16 + l15, seg = kk * 4 + kb;
      boff[j][kk] = 4096 + row * 64 + ((seg ^ (row & 7)) << 3);
    }

  f32x4 acc[4][2];
#pragma unroll
  for (int i = 0; i < 4; ++i)
#pragma unroll
    for (int j = 0; j < 2; ++j)
#pragma unroll
      for (int q = 0; q < 4; ++q) acc[i][j][q] = 0.f;

  auto stage = [&](int ks, int buf) {
    const int tap  = ks >> 2;
    const int aofs = (tap + 3 * (tap / 3)) * 256 + ((ks & 3) << 6);
    const int bofs = ks << 6;
    unsigned short* sb = &smem[buf * 12288];
    gload16(asrc[0] + aofs, sb + t * 8);
    gload16(asrc[1] + aofs, sb + t * 8 + 2048);
    gload16(bsrc[0] + bofs, sb + 4096 + t * 8);
    gload16(bsrc[1] + bofs, sb + 4096 + t * 8 + 2048);
    gload16(bsrc[2] + bofs, sb + 4096 + t * 8 + 4096);
    gload16(bsrc[3] + bofs, sb + 4096 + t * 8 + 6144);
  };

  stage(0, 0);
  __syncthreads();

  int buf = 0;
  for (int ks = 0; ks < 36; ++ks) {
    if (ks + 1 < 36) stage(ks + 1, buf ^ 1);
    const unsigned short* base = &smem[buf * 12288];
    bf16x8 af[4][2], bfr[2][2];
#pragma unroll
    for (int i = 0; i < 4; ++i)
#pragma unroll
      for (int kk = 0; kk < 2; ++kk) af[i][kk] = *(const bf16x8*)(base + aoff[i][kk]);
#pragma unroll
    for (int j = 0; j < 2; ++j)
#pragma unroll
      for (int kk = 0; kk < 2; ++kk) bfr[j][kk] = *(const bf16x8*)(base + boff[j][kk]);
#pragma unroll
    for (int kk = 0; kk < 2; ++kk)
#pragma unroll
      for (int i = 0; i < 4; ++i)
#pragma unroll
        for (int j = 0; j < 2; ++j)
          acc[i][j] = __builtin_amdgcn_mfma_f32_16x16x32_bf16(af[i][kk], bfr[j][kk], acc[i][j], 0, 0, 0);
    __syncthreads();
    buf ^= 1;
  }

#pragma unroll
  for (int j = 0; j < 2; ++j) {
    const int oc  = bn + wid * 32 + j * 16 + l15;
    const int cap = oc >> 3, ii = oc & 7;
    const float bv = convB[oc];
#pragma unroll
    for (int i = 0; i < 4; ++i) {
#pragma unroll
      for (int q = 0; q < 4; ++q) {
        const int row = bm + i * 16 + kb * 4 + q;
        const int b = row >> 4, p = row & 15;
        const float val = acc[i][j][q] + bv;
        float sq = val * val;
        sq += __shfl_xor(sq, 1);
        sq += __shfl_xor(sq, 2);
        sq += __shfl_xor(sq, 4);
        const float scale = sq / (1.f + sq) / sqrtf(sq + 1e-8f);
        U[(size_t)b * 4096 + cap * 128 + p * 8 + ii] = f2h(val * scale);
      }
    }
  }
}

// =====================================================================
// Transforms: one fused small-prep kernel + the W1 transpose
// =====================================================================
#define NX_ITEMS (BSZ * INDIM / 4)      // 196608
#define NW_ITEMS (NCAP * 640 / 4)       // 81920
#define NC_ITEMS 65536
#define NB_ITEMS PROJ                   // 9216
#define PREP_TOTAL (NX_ITEMS + NW_ITEMS + NC_ITEMS + NB_ITEMS)

__global__ __launch_bounds__(256) void prep_small(
    const float* __restrict__ x, unsigned short* __restrict__ xb,
    const float* __restrict__ Wr, __half2* __restrict__ wrh,
    const float* __restrict__ convW, unsigned short* __restrict__ wt2,
    const float* __restrict__ b1, float* __restrict__ pb1) {
  const int id = blockIdx.x * 256 + threadIdx.x;
  if (id < NX_ITEMS) {
    float4 v = ((const float4*)x)[id];
    ushort4 o;
    o.x = f2bf(v.x); o.y = f2bf(v.y); o.z = f2bf(v.z); o.w = f2bf(v.w);
    ((ushort4*)xb)[id] = o;
  } else if (id < NX_ITEMS + NW_ITEMS) {
    const int i = id - NX_ITEMS;
    float4 v = ((const float4*)Wr)[i];
    wrh[i * 2]     = __floats2half2_rn(v.x, v.y);
    wrh[i * 2 + 1] = __floats2half2_rn(v.z, v.w);
  } else if (id < NX_ITEMS + NW_ITEMS + NC_ITEMS) {
    const int i = id - NX_ITEMS - NW_ITEMS;
    const int oc = i >> 8, ic = i & 255;
    const float* s = convW + (size_t)i * 9;
#pragma unroll
    for (int tap = 0; tap < 9; ++tap)
      wt2[(size_t)oc * K2 + tap * 256 + ic] = f2bf(s[tap]);
  } else if (id < PREP_TOTAL) {
    const int n = id - NX_ITEMS - NW_ITEMS - NC_ITEMS;
    pb1[(n % 36) * 256 + n / 36] = b1[n];
  }
}

__global__ __launch_bounds__(256) void transpose_w1_perm(const float* __restrict__ W,
                                                         unsigned short* __restrict__ Wt) {
  __shared__ float tile[32][33];
  const int n0 = blockIdx.x * 32, k0 = blockIdx.y * 32;
  const int r = threadIdx.x >> 3, c = (threadIdx.x & 7) * 4;
  float4 v = *(const float4*)(W + (size_t)(k0 + r) * PROJ + n0 + c);
  tile[r][c] = v.x; tile[r][c + 1] = v.y; tile[r][c + 2] = v.z; tile[r][c + 3] = v.w;
  __syncthreads();
  ushort4 o;
  o.x = f2bf(tile[c + 0][r]); o.y = f2bf(tile[c + 1][r]);
  o.z = f2bf(tile[c + 2][r]); o.w = f2bf(tile[c + 3][r]);
  const int nn = n0 + r;
  const int prow = (nn % 36) * 256 + nn / 36;
  *(ushort4*)(Wt + (size_t)prow * INDIM + k0 + c) = o;
}

// =====================================================================
// route_fused<MODE>: fused routing pass — recomputes u_hat fragments
// via MFMA in-register, per-(b,n) softmax, weighted s partial accumulate.
//   MODE 0: c = 1 (0.2 applied at consume)
//   MODE 1: v_prev = v0 = per-o squash(0.2 * sum sp0)
//   MODE 2: v_prev = v0 + v1 (linearity)
// NOTE: squash norm is PER OUTPUT CAPSULE o (16 dims), not over all 80.
// Lane (kb,l15): cfr[jn][qq] = u_hat[b=gb+l15][n][od=jn*16+kb*4+qq]
// grid (BSZ/16, 8), 512 threads (8 waves x 8 n each).
// =====================================================================
template <int MODE>
__global__ __launch_bounds__(512) void route_fused(
    const unsigned short* __restrict__ U,    // [1024][512][8] fp16
    const unsigned short* __restrict__ Wrh,  // [512][80][8] fp16
    const float* __restrict__ sp0,           // [8][1024][80] (MODE>=1)
    const float* __restrict__ sp1,           // [8][1024][80] (MODE==2)
    float* __restrict__ spout) {             // [8][1024][80]
  __shared__ float sred[8][16][80];  // 40 KB
  __shared__ float s0l[16][81];
  __shared__ float s1l[16][81];
  __shared__ float scl[16][5][2];
  const int mt = blockIdx.x, q = blockIdx.y;
  const int t = threadIdx.x, wid = t >> 6, lane = t & 63;
  const int l15 = lane & 15, kb = lane >> 4;
  const int gb = mt * 16;

  float vreg[5][4];
  if (MODE >= 1) {
    for (int item = t; item < 1280; item += 512) {
      const int bl = item / 80, od = item % 80;
      float a0 = 0.f, a1 = 0.f;
#pragma unroll
      for (int g = 0; g < 8; ++g) {
        a0 += sp0[((size_t)g * BSZ + gb + bl) * 80 + od];
        if (MODE == 2) a1 += sp1[((size_t)g * BSZ + gb + bl) * 80 + od];
      }
      s0l[bl][od] = a0 * 0.2f;
      if (MODE == 2) s1l[bl][od] = a1;
    }
    __syncthreads();
    // per-(b,o) squash scale: norm over the o-capsule's 16 dims ONLY
    if (t < 80) {
      const int bl = t / 5, o = t % 5;
      float sq0 = 0.f, sq1 = 0.f;
#pragma unroll
      for (int d = 0; d < 16; ++d) {
        const float x0 = s0l[bl][o * 16 + d];
        sq0 += x0 * x0;
        if (MODE == 2) { const float x1 = s1l[bl][o * 16 + d]; sq1 += x1 * x1; }
      }
      scl[bl][o][0] = sq0 / (1.f + sq0) / sqrtf(sq0 + 1e-8f);
      if (MODE == 2) scl[bl][o][1] = sq1 / (1.f + sq1) / sqrtf(sq1 + 1e-8f);
    }
    __syncthreads();
#pragma unroll
    for (int jn = 0; jn < 5; ++jn) {
      const float sc0 = scl[l15][jn][0];
      const float sc1 = (MODE == 2) ? scl[l15][jn][1] : 0.f;
#pragma unroll
      for (int qq = 0; qq < 4; ++qq) {
        const int od = jn * 16 + kb * 4 + qq;
        float v = s0l[l15][od] * sc0;
        if (MODE == 2) v += s1l[l15][od] * sc1;
        vreg[jn][qq] = v;
      }
    }
  }

  f32x4 sacc[5];
#pragma unroll
  for (int jn = 0; jn < 5; ++jn)
#pragma unroll
    for (int qq = 0; qq < 4; ++qq) sacc[jn][qq] = 0.f;

  const uint4 zz = make_uint4(0, 0, 0, 0);
#pragma unroll
  for (int i = 0; i < 8; ++i) {
    const int n = q * 64 + wid * 8 + i;
    uint4 av = zz;
    if (kb == 0) av = *(const uint4*)(U + (size_t)(gb + l15) * 4096 + n * 8);
    const f16x8 uf = __builtin_bit_cast(f16x8, av);
    f32x4 cfr[5];
#pragma unroll
    for (int jn = 0; jn < 5; ++jn) {
      uint4 wv = zz;
      if (kb == 0) wv = *(const uint4*)(Wrh + (size_t)n * 640 + (jn * 16 + l15) * 8);
      f32x4 z;
      z[0] = 0.f; z[1] = 0.f; z[2] = 0.f; z[3] = 0.f;
      cfr[jn] = __builtin_amdgcn_mfma_f32_16x16x32_f16(
          __builtin_bit_cast(f16x8, wv), uf, z, 0, 0, 0);
    }
    float c[5];
    if (MODE == 0) {
#pragma unroll
      for (int o = 0; o < 5; ++o) c[o] = 1.f;
    } else {
      float a[5];
#pragma unroll
      for (int jn = 0; jn < 5; ++jn) {
        float d = cfr[jn][0] * vreg[jn][0] + cfr[jn][1] * vreg[jn][1] +
                  cfr[jn][2] * vreg[jn][2] + cfr[jn][3] * vreg[jn][3];
        d += __shfl_xor(d, 16);
        d += __shfl_xor(d, 32);
        a[jn] = d;
      }
      float m = fmaxf(fmaxf(fmaxf(a[0], a[1]), fmaxf(a[2], a[3])), a[4]);
      float es = 0.f;
#pragma unroll
      for (int o = 0; o < 5; ++o) { c[o] = __expf(a[o] - m); es += c[o]; }
      const float inv = 1.f / es;
#pragma unroll
      for (int o = 0; o < 5; ++o) c[o] *= inv;
    }
#pragma unroll
    for (int jn = 0; jn < 5; ++jn)
#pragma unroll
      for (int qq = 0; qq < 4; ++qq) sacc[jn][qq] += c[jn] * cfr[jn][qq];
  }

  // cross-wave combine, write s partials
#pragma unroll
  for (int jn = 0; jn < 5; ++jn)
#pragma unroll
    for (int qq = 0; qq < 4; ++qq)
      sred[wid][l15][jn * 16 + kb * 4 + qq] = sacc[jn][qq];
  __syncthreads();
#pragma unroll
  for (int k = 0; k < 3; ++k) {
    const int id = t + k * 512;
    if (id < 1280) {
      const int bb = id / 80, od = id % 80;
      float val = 0.f;
#pragma unroll
      for (int w = 0; w < 8; ++w) val += sred[w][bb][od];
      spout[((size_t)q * BSZ + gb + bb) * 80 + od] = val;
    }
  }
}

// final: v2 = per-o squash(sum sp2), class_probs = |v2| (per-o norm)
__global__ __launch_bounds__(128) void route_emit(
    const float* __restrict__ sp2, float* __restrict__ out) {
  const int b = blockIdx.x, t = threadIdx.x;
  if (t < 80) {
    float s = 0.f;
#pragma unroll
    for (int g = 0; g < 8; ++g) s += sp2[((size_t)g * BSZ + b) * 80 + t];
    float sq = s * s;
    sq += __shfl_xor(sq, 1);
    sq += __shfl_xor(sq, 2);
    sq += __shfl_xor(sq, 4);
    sq += __shfl_xor(sq, 8);
    const float scale = sq / (1.f + sq) / sqrtf(sq + 1e-8f);
    const float vn = s * scale;
    out[5 * BSZ + (size_t)b * 80 + t] = vn;
    float vv = vn * vn;
    vv += __shfl_xor(vv, 1);
    vv += __shfl_xor(vv, 2);
    vv += __shfl_xor(vv, 4);
    vv += __shfl_xor(vv, 8);
    if ((t & 15) == 0) out[(size_t)b * 5 + (t >> 4)] = sqrtf(vv);
  }
}

// =====================================================================
extern "C" void kernel_launch(void* const* d_in, const int* in_sizes, int n_in,
                              void* d_out, int out_size, void* d_ws, size_t ws_size,
                              hipStream_t stream) {
  const float* x     = (const float*)d_in[0];
  const float* W1    = (const float*)d_in[1];
  const float* b1    = (const float*)d_in[2];
  const float* convW = (const float*)d_in[3];
  const float* convB = (const float*)d_in[4];
  const float* Wr    = (const float*)d_in[5];
  float* out = (float*)d_out;

  char* base = (char*)d_ws;
  size_t off = 0;
  auto alloc = [&](size_t bytes) { size_t o = off; off = (off + bytes + 255) & ~(size_t)255; return o; };
  const size_t o_wrh = alloc((size_t)NCAP * 640 * 2);      // 0.66 MB fp16
  const size_t o_u   = alloc((size_t)BSZ * 4096 * 2);      // 8.4 MB fp16
  const size_t o_sp0 = alloc((size_t)8 * BSZ * 80 * 4);    // 2.6 MB f32
  const size_t o_sp1 = alloc((size_t)8 * BSZ * 80 * 4);    // 2.6 MB f32
  const size_t o_sp2 = alloc((size_t)8 * BSZ * 80 * 4);    // 2.6 MB f32
  const size_t o_ht  = alloc((size_t)BSZ * PROJ * 2);      // 18.9 MB bf16
  const size_t o_w1t = alloc((size_t)PROJ * INDIM * 2);    // 14.2 MB bf16
  const size_t o_xb  = alloc((size_t)BSZ * INDIM * 2);     // 1.6 MB bf16
  const size_t o_wt2 = alloc((size_t)256 * K2 * 2);        // 1.2 MB bf16
  const size_t o_pb1 = alloc((size_t)PROJ * 4);            // 36 KB f32

  unsigned short* wrh = (unsigned short*)(base + o_wrh);
  unsigned short* u   = (unsigned short*)(base + o_u);
  float*          sp0 = (float*)(base + o_sp0);
  float*          sp1 = (float*)(base + o_sp1);
  float*          sp2 = (float*)(base + o_sp2);
  unsigned short* ht  = (unsigned short*)(base + o_ht);
  unsigned short* w1t = (unsigned short*)(base + o_w1t);
  unsigned short* xb  = (unsigned short*)(base + o_xb);
  unsigned short* wt2 = (unsigned short*)(base + o_wt2);
  float*          pb1 = (float*)(base + o_pb1);

  prep_small<<<(PREP_TOTAL + 255) / 256, 256, 0, stream>>>(
      x, xb, Wr, (__half2*)wrh, convW, wt2, b1, pb1);
  transpose_w1_perm<<<dim3(PROJ / 32, INDIM / 32), 256, 0, stream>>>(W1, w1t);

  // ht = relu(x @ W1 + b1) in [b][sp][c] layout
  mfma_gemm<1, 1><<<dim3(PROJ / 128, BSZ / 128), 256, 0, stream>>>(
      xb, w1t, pb1, (void*)ht, BSZ, PROJ, INDIM);

  // conv + squash fused (implicit im2col, BK=64, u written directly)
  conv_gemm_sq<<<dim3(2, 256), 256, 0, stream>>>(ht, wt2, convB, u);

  // fully fused routing: 3 streaming passes + emit, no u_hat tensor
  dim3 fg(BSZ / 16, 8);
  route_fused<0><<<fg, 512, 0, stream>>>(u, wrh, nullptr, nullptr, sp0);
  route_fused<1><<<fg, 512, 0, stream>>>(u, wrh, sp0, nullptr, sp1);
  route_fused<2><<<fg, 512, 0, stream>>>(u, wrh, sp0, sp1, sp2);
  route_emit<<<BSZ, 128, 0, stream>>>(sp2, out);
}